// Round 12
// baseline (197.361 us; speedup 1.0000x reference)
//
#include <hip/hip_runtime.h>

#define N_NODES 40000
#define E_EDGES 640000
#define E_TOT   (E_EDGES + N_NODES)
#define SCAN_BLOCKS ((N_NODES + 255) / 256)   // 157
#define G1_BLOCKS 1250                        // 625 row-tiles x 2 col-panels

typedef unsigned int uint;
typedef unsigned short ushort;

// bf16 helpers (RNE pack, cheap unpack)
__device__ __forceinline__ ushort f2bf(float f) {
    uint u = __float_as_uint(f);
    u += 0x7FFFu + ((u >> 16) & 1u);
    return (ushort)(u >> 16);
}
__device__ __forceinline__ uint pk_bf(float lo, float hi) {
    return (uint)f2bf(lo) | ((uint)f2bf(hi) << 16);
}
__device__ __forceinline__ float bf_lo(uint w) { return __uint_as_float(w << 16); }
__device__ __forceinline__ float bf_hi(uint w) { return __uint_as_float(w & 0xFFFF0000u); }

// ===========================================================================
// init_cnt: cnt[i] = 1 (self-loop baked in).
// ===========================================================================
__global__ __launch_bounds__(256) void init_cnt_kernel(int4* __restrict__ cnt4)
{
    const int i = blockIdx.x * 256 + threadIdx.x;
    if (i < 40064 / 4) cnt4[i] = make_int4(1, 1, 1, 1);
}

// hist: 1 edge/thread (max TLP for the scattered atomic).
__global__ __launch_bounds__(256) void hist_kernel(
    const int* __restrict__ eidx, int* __restrict__ cnt)
{
    const int e = blockIdx.x * 256 + threadIdx.x;
    if (e < E_EDGES) atomicAdd(&cnt[eidx[E_EDGES + e]], 1);
}

// ===========================================================================
// GEMM1: h1 = x @ W1 [40000x128 @ 128x128]; h1 bf16; fused attention coeffs.
// 64x64 tile, 32 KB LDS, conflict-free.
// ===========================================================================
__global__ __launch_bounds__(256) void gemm1_kernel(
    const float* __restrict__ x, const float* __restrict__ W,
    const float* __restrict__ a_src, const float* __restrict__ a_dst,
    ushort* __restrict__ h1b, float* __restrict__ asrc, float* __restrict__ adst)
{
    __shared__ float Ws[128 * 64];   // 32 KB
    const int cb = blockIdx.x & 1;
    const int row0 = (blockIdx.x >> 1) * 64;
    {
        const float4* Wg = (const float4*)W;
        float4* Wl = (float4*)Ws;
        for (int i = threadIdx.x; i < 128 * 64 / 4; i += 256) {
            const int r = i >> 4, c = i & 15;
            Wl[i] = Wg[r * 32 + cb * 16 + c];
        }
    }
    __syncthreads();
    const int tx = threadIdx.x & 15;
    const int ty = threadIdx.x >> 4;

    float acc[4][4];
#pragma unroll
    for (int r = 0; r < 4; ++r)
#pragma unroll
        for (int c = 0; c < 4; ++c) acc[r][c] = 0.f;

    for (int k0 = 0; k0 < 128; k0 += 4) {
        float xv[4][4];
#pragma unroll
        for (int r = 0; r < 4; ++r) {
            float4 t = *(const float4*)&x[(size_t)(row0 + ty * 4 + r) * 128 + k0];
            xv[r][0] = t.x; xv[r][1] = t.y; xv[r][2] = t.z; xv[r][3] = t.w;
        }
#pragma unroll
        for (int kk = 0; kk < 4; ++kk) {
            float4 w = *(const float4*)&Ws[(k0 + kk) * 64 + tx * 4];
            float wreg[4] = { w.x, w.y, w.z, w.w };
#pragma unroll
            for (int r = 0; r < 4; ++r)
#pragma unroll
                for (int c = 0; c < 4; ++c)
                    acc[r][c] = fmaf(xv[r][kk], wreg[c], acc[r][c]);
        }
    }

    const int head = 2 * cb + (tx >> 3);
    const int coff = (tx & 7) * 4;
    float as[4], ad[4];
#pragma unroll
    for (int c = 0; c < 4; ++c) {
        as[c] = a_src[head * 32 + coff + c];
        ad[c] = a_dst[head * 32 + coff + c];
    }
#pragma unroll
    for (int r = 0; r < 4; ++r) {
        const int n = row0 + ty * 4 + r;
        uint2 o;
        o.x = pk_bf(acc[r][0], acc[r][1]);
        o.y = pk_bf(acc[r][2], acc[r][3]);
        *(uint2*)&h1b[(size_t)n * 128 + cb * 64 + tx * 4] = o;
        float ps = 0.f, pd = 0.f;
#pragma unroll
        for (int c = 0; c < 4; ++c) {
            ps = fmaf(acc[r][c], as[c], ps);
            pd = fmaf(acc[r][c], ad[c], pd);
        }
        ps += __shfl_xor(ps, 1); ps += __shfl_xor(ps, 2); ps += __shfl_xor(ps, 4);
        pd += __shfl_xor(pd, 1); pd += __shfl_xor(pd, 2); pd += __shfl_xor(pd, 4);
        if ((tx & 7) == 0) {
            asrc[n * 4 + head] = ps;
            adst[n * 4 + head] = pd;
        }
    }
}

// ===========================================================================
// scanA/scanB/scanC: CSR prefix machinery (as R11).
// ===========================================================================
__global__ __launch_bounds__(256) void scanA_kernel(
    const int* __restrict__ cnt, int* __restrict__ rowptr, int* __restrict__ bsum)
{
    const int i = blockIdx.x * 256 + threadIdx.x;
    const int lane = threadIdx.x & 63;
    const int wave = threadIdx.x >> 6;
    const int v = (i < N_NODES) ? cnt[i] : 0;
    int incl = v;
#pragma unroll
    for (int off = 1; off < 64; off <<= 1) {
        int u = __shfl_up(incl, off);
        if (lane >= off) incl += u;
    }
    __shared__ int ws[4];
    if (lane == 63) ws[wave] = incl;
    __syncthreads();
    int woff = 0;
    if (wave > 0) woff += ws[0];
    if (wave > 1) woff += ws[1];
    if (wave > 2) woff += ws[2];
    if (i <= N_NODES) rowptr[i] = woff + incl - v;
    if (threadIdx.x == 255) bsum[blockIdx.x] = woff + incl;
}

__global__ __launch_bounds__(256) void scanB_kernel(int* __restrict__ bsum)
{
    const int t = threadIdx.x;
    const int lane = t & 63;
    const int wave = t >> 6;
    const int v = (t < SCAN_BLOCKS) ? bsum[t] : 0;
    int incl = v;
#pragma unroll
    for (int off = 1; off < 64; off <<= 1) {
        int u = __shfl_up(incl, off);
        if (lane >= off) incl += u;
    }
    __shared__ int ws[4];
    if (lane == 63) ws[wave] = incl;
    __syncthreads();
    int woff = 0;
    if (wave > 0) woff += ws[0];
    if (wave > 1) woff += ws[1];
    if (wave > 2) woff += ws[2];
    if (t < SCAN_BLOCKS) bsum[t] = woff + incl - v;
}

__global__ __launch_bounds__(256) void scanC_kernel(
    const int* __restrict__ rowptr, const int* __restrict__ bsum,
    int* __restrict__ rowfin, int* __restrict__ cursor)
{
    const int i = blockIdx.x * 256 + threadIdx.x;
    if (i > N_NODES) return;
    const int base = rowptr[i] + bsum[i >> 8];
    rowfin[i] = base;
    if (i < N_NODES) cursor[i] = base;
}

// fill: 1 edge/thread (max TLP), cursor atomic + scattered write.
__global__ __launch_bounds__(256) void fill_kernel(
    const int* __restrict__ eidx, int* __restrict__ cursor,
    int* __restrict__ esrc)
{
    const int e = blockIdx.x * 256 + threadIdx.x;
    if (e >= E_TOT) return;
    int s, d;
    if (e < E_EDGES) { s = eidx[e]; d = eidx[E_EDGES + e]; }
    else             { s = d = e - E_EDGES; }
    esrc[atomicAdd(&cursor[d], 1)] = s;
}

// ===========================================================================
// FUSED gather1 + gemm2: one wave per dst node.
// Phase A: CSR gather of bf16 h1 rows -> softmax-weighted agg row (norm +
//          bias + ELU) kept in LDS (agg1 never touches global).
// Phase B: h2[n,:] = aggRow @ W2 (128x32, W2 in LDS) + layer-2 attention dots.
// ===========================================================================
__global__ __launch_bounds__(256) void gather1_gemm2_kernel(
    const int* __restrict__ rowfin,
    const int* __restrict__ esrc, const float* __restrict__ asrc,
    const float* __restrict__ adst,
    const ushort* __restrict__ h1b, const float* __restrict__ b,
    const float* __restrict__ W2,
    const float* __restrict__ a_src2, const float* __restrict__ a_dst2,
    float* __restrict__ h2, float* __restrict__ asrc2, float* __restrict__ adst2)
{
    __shared__ float Ws2[128 * 32];   // 16 KB
    __shared__ float aggL[4][128];    // 2 KB
    __shared__ float asv[32], adv[32];
    {
        const float4* Wg = (const float4*)W2;
        float4* Wl = (float4*)Ws2;
        for (int i = threadIdx.x; i < 128 * 32 / 4; i += 256) Wl[i] = Wg[i];
        if (threadIdx.x < 32) {
            asv[threadIdx.x] = a_src2[threadIdx.x];
            adv[threadIdx.x] = a_dst2[threadIdx.x];
        }
    }
    __syncthreads();

    const int wv = threadIdx.x >> 6;
    const int lane = threadIdx.x & 63;
    const int node = blockIdx.x * 4 + wv;   // grid exact: 10000*4 = 40000
    const int head = lane >> 4;
    const float ad = adst[node * 4 + head];
    const int beg = rowfin[node], end = rowfin[node + 1];
    float acc0 = 0.f, acc1 = 0.f, den = 0.f;

    int i = beg;
    for (; i + 8 <= end; i += 8) {
        int s[8];
        float a[8];
        uint w[8];
#pragma unroll
        for (int j = 0; j < 8; ++j) s[j] = esrc[i + j];
#pragma unroll
        for (int j = 0; j < 8; ++j) a[j] = asrc[s[j] * 4 + head];
#pragma unroll
        for (int j = 0; j < 8; ++j)
            w[j] = *(const uint*)&h1b[(size_t)s[j] * 128 + lane * 2];
#pragma unroll
        for (int j = 0; j < 8; ++j) {
            float v = a[j] + ad; v = v > 0.f ? v : 0.2f * v;
            const float e = __expf(v);
            den += e;
            acc0 = fmaf(e, bf_lo(w[j]), acc0);
            acc1 = fmaf(e, bf_hi(w[j]), acc1);
        }
    }
    for (; i < end; ++i) {
        const int s = esrc[i];
        float av = asrc[s * 4 + head] + ad;
        av = av > 0.f ? av : 0.2f * av;
        const float ex = __expf(av);
        const uint w = *(const uint*)&h1b[(size_t)s * 128 + lane * 2];
        den += ex;
        acc0 = fmaf(ex, bf_lo(w), acc0);
        acc1 = fmaf(ex, bf_hi(w), acc1);
    }

    const float inv = 1.f / (den + 1e-16f);
    const float2 bv = *(const float2*)&b[lane * 2];
    float o0 = acc0 * inv + bv.x;
    float o1 = acc1 * inv + bv.y;
    o0 = o0 > 0.f ? o0 : expm1f(o0);
    o1 = o1 > 0.f ? o1 : expm1f(o1);
    aggL[wv][lane * 2]     = o0;
    aggL[wv][lane * 2 + 1] = o1;
    __syncthreads();   // all 256 threads present (exact grid)

    // ---- Phase B: h2 row = aggRow @ W2; attention dots ----
    const int half = lane >> 5;
    const int c = lane & 31;
    float v = 0.f;
#pragma unroll 8
    for (int j = 0; j < 64; ++j) {
        const int k = half * 64 + j;
        v = fmaf(aggL[wv][k], Ws2[k * 32 + c], v);
    }
    v += __shfl_xor(v, 32);          // both halves now hold full dot
    float ps = v * asv[c];
    float pd = v * adv[c];
    ps += __shfl_xor(ps, 1); ps += __shfl_xor(ps, 2); ps += __shfl_xor(ps, 4);
    ps += __shfl_xor(ps, 8); ps += __shfl_xor(ps, 16);
    pd += __shfl_xor(pd, 1); pd += __shfl_xor(pd, 2); pd += __shfl_xor(pd, 4);
    pd += __shfl_xor(pd, 8); pd += __shfl_xor(pd, 16);
    if (lane < 32) h2[(size_t)node * 32 + c] = v;
    if (lane == 0) { asrc2[node] = ps; adst2[node] = pd; }
}

// ===========================================================================
// FUSED gather2 + out_gemm: 8 nodes per block (32 lanes each).
// Phase A: gather h2 rows -> agg2 rows in LDS (never global).
// Phase B: out[n,:] = agg2Row @ W_out + b_out  (32x112, W_out in LDS).
// ===========================================================================
__global__ __launch_bounds__(256) void gather2_out_kernel(
    const int* __restrict__ rowfin,
    const int* __restrict__ esrc,
    const float* __restrict__ asrc, const float* __restrict__ adst,
    const float* __restrict__ h2, const float* __restrict__ b,
    const float* __restrict__ W_out, const float* __restrict__ b_out,
    float* __restrict__ out)
{
    __shared__ float Wo[32 * 112];   // 14 KB
    __shared__ float agL[8][32];     // 1 KB
    __shared__ float boL[112];
    {
        const float4* Wg = (const float4*)W_out;
        float4* Wl = (float4*)Wo;
        for (int i = threadIdx.x; i < 32 * 112 / 4; i += 256) Wl[i] = Wg[i];
        if (threadIdx.x < 112) boL[threadIdx.x] = b_out[threadIdx.x];
    }
    __syncthreads();

    const int nl = threadIdx.x >> 5;        // 0..7
    const int c  = threadIdx.x & 31;
    const int node = blockIdx.x * 8 + nl;   // grid exact: 5000*8 = 40000
    const float ad = adst[node];
    const int beg = rowfin[node], end = rowfin[node + 1];
    float acc = 0.f, den = 0.f;

    int i = beg;
    for (; i + 8 <= end; i += 8) {
        int s[8];
        float a[8], h[8];
#pragma unroll
        for (int j = 0; j < 8; ++j) s[j] = esrc[i + j];
#pragma unroll
        for (int j = 0; j < 8; ++j) a[j] = asrc[s[j]];
#pragma unroll
        for (int j = 0; j < 8; ++j) h[j] = h2[(size_t)s[j] * 32 + c];
#pragma unroll
        for (int j = 0; j < 8; ++j) {
            float v = a[j] + ad; v = v > 0.f ? v : 0.2f * v;
            const float e = __expf(v);
            den += e;
            acc = fmaf(e, h[j], acc);
        }
    }
    for (; i < end; ++i) {
        const int s = esrc[i];
        float av = asrc[s] + ad;
        av = av > 0.f ? av : 0.2f * av;
        const float ex = __expf(av);
        den += ex;
        acc = fmaf(ex, h2[(size_t)s * 32 + c], acc);
    }

    const float inv = 1.f / (den + 1e-16f);
    float o = acc * inv + b[c];
    o = o > 0.f ? o : expm1f(o);
    agL[nl][c] = o;
    __syncthreads();

    // ---- Phase B: 8 nodes x 112 cols = 896 outputs, 4 per thread ----
#pragma unroll
    for (int it = 0; it < 4; ++it) {
        const int oidx = threadIdx.x + it * 256;
        if (oidx < 8 * 112) {
            const int n = oidx / 112, col = oidx % 112;
            float v = boL[col];
#pragma unroll
            for (int k = 0; k < 32; ++k)
                v = fmaf(agL[n][k], Wo[k * 112 + col], v);
            out[(size_t)(blockIdx.x * 8 + n) * 112 + col] = v;
        }
    }
}

// ===========================================================================
extern "C" void kernel_launch(void* const* d_in, const int* in_sizes, int n_in,
                              void* d_out, int out_size, void* d_ws, size_t ws_size,
                              hipStream_t stream) {
    const float* x      = (const float*)d_in[0];
    const int*   eidx   = (const int*)d_in[1];
    const float* W1     = (const float*)d_in[2];
    const float* a_src1 = (const float*)d_in[3];
    const float* a_dst1 = (const float*)d_in[4];
    const float* b1     = (const float*)d_in[5];
    const float* W2     = (const float*)d_in[6];
    const float* a_src2 = (const float*)d_in[7];
    const float* a_dst2 = (const float*)d_in[8];
    const float* b2     = (const float*)d_in[9];
    const float* W_out  = (const float*)d_in[10];
    const float* b_out  = (const float*)d_in[11];
    float* out = (float*)d_out;

    // ---- workspace layout (~20 MB) ----
    int* rowptr = (int*)d_ws;                 // 40064
    int* rowfin = rowptr + 40064;             // 40064
    int* cnt    = rowfin + 40064;             // 40064
    int* cursor = cnt + 40064;                // 40064
    int* bsum   = cursor + 40064;             // 256
    int* esrc   = bsum + 256;                 // 680000
    ushort* h1b  = (ushort*)(esrc + 680000);  // 40000*128 bf16
    float* asrc1 = (float*)(h1b + 5120000);   // 40000*4
    float* adst1 = asrc1 + 160000;            // 40000*4
    float* h2    = adst1 + 160000;            // 40000*32 (no overlay: h1b live)
    float* asrc2 = h2 + 1280000;              // 40000
    float* adst2 = asrc2 + 40000;             // 40000

    // Layer-1 GEMM (independent of CSR build)
    gemm1_kernel<<<G1_BLOCKS, 256, 0, stream>>>(x, W1, a_src1, a_dst1, h1b,
                                                asrc1, adst1);
    // CSR build
    init_cnt_kernel<<<(40064 / 4 + 255) / 256, 256, 0, stream>>>((int4*)cnt);
    hist_kernel<<<(E_EDGES + 255) / 256, 256, 0, stream>>>(eidx, cnt);
    scanA_kernel<<<SCAN_BLOCKS, 256, 0, stream>>>(cnt, rowptr, bsum);
    scanB_kernel<<<1, 256, 0, stream>>>(bsum);
    scanC_kernel<<<SCAN_BLOCKS, 256, 0, stream>>>(rowptr, bsum, rowfin, cursor);
    fill_kernel<<<(E_TOT + 255) / 256, 256, 0, stream>>>(eidx, cursor, esrc);

    // Layer 1 aggregate + Layer-2 GEMM (fused)
    gather1_gemm2_kernel<<<10000, 256, 0, stream>>>(
        rowfin, esrc, asrc1, adst1, h1b, b1, W2, a_src2, a_dst2,
        h2, asrc2, adst2);

    // Layer 2 aggregate + output projection (fused)
    gather2_out_kernel<<<5000, 256, 0, stream>>>(
        rowfin, esrc, asrc2, adst2, h2, b2, W_out, b_out, out);
}